// Round 6
// baseline (2067.705 us; speedup 1.0000x reference)
//
#include <hip/hip_runtime.h>

// VisionMamba: B=2, L=1024 (16x8x8), d=384, 12 layers, dstate=16, dconv=4, dtrank=24
// Inputs are float32 (runtime-detected via Dskip; bf16 also supported).
// GEMMs: bf16 MFMA, 32x32 block tiles (4 waves x 16x16 frag) for occupancy.
// ws ~18.5MB (round-5-proven layout style, no aliasing).

#define NTOK 2048

typedef short bf16x8 __attribute__((ext_vector_type(8)));
typedef float f32x4 __attribute__((ext_vector_type(4)));
typedef unsigned short us4 __attribute__((ext_vector_type(4)));

__device__ __forceinline__ float bf2f(unsigned short u) {
    return __uint_as_float(((unsigned)u) << 16);
}
__device__ __forceinline__ unsigned short f2bf(float f) {
    unsigned u = __float_as_uint(f);
    u += 0x7fffu + ((u >> 16) & 1u);
    return (unsigned short)(u >> 16);
}
__device__ __forceinline__ float siluf(float x) { return x / (1.f + expf(-x)); }

__device__ __forceinline__ float ldr(const void* p, size_t i, int bf) {
    if (bf) return bf2f(((const unsigned short*)p)[i]);
    return ((const float*)p)[i];
}
template<int BF>
__device__ __forceinline__ float ld(const void* p, size_t i) {
    if (BF) return bf2f(((const unsigned short*)p)[i]);
    return ((const float*)p)[i];
}

__global__ void detect_kernel(const void* dskip, int* flag) {
    flag[0] = (((const unsigned short*)dskip)[0] == 0x3F80u) ? 1 : 0;
}

// ---------------- patch_w transpose: [4096][384] -> wtP[384][4096] bf16 ----------------
__global__ __launch_bounds__(256)
void transposeP_kernel(const int* flag, const void* pw, unsigned short* wtP)
{
    __shared__ unsigned short Ts[32 * 36];
    const int bid = blockIdx.x;           // 1536 = 128 kb x 12 nb
    const int kb = bid / 12, nb = bid % 12;
    const int tid = threadIdx.x;
    const int r = tid >> 3, c0 = (tid & 7) * 4;
    const int BF = *flag;
#pragma unroll
    for (int i = 0; i < 4; i++) {
        size_t si = (size_t)(kb * 32 + r) * 384 + nb * 32 + c0 + i;
        Ts[(c0 + i) * 36 + r] = f2bf(ldr(pw, si, BF));
    }
    __syncthreads();
    *(us4*)(wtP + (size_t)(nb * 32 + r) * 4096 + kb * 32 + c0) = *(const us4*)&Ts[r * 36 + c0];
}

// ---------- per-layer transposes: in_proj->wtL[768][384], out_proj->wtOl[384][384],
// ---------- x_proj[384][56] -> wtXp[56][384] (bf16)
__global__ __launch_bounds__(256)
void transposeL_kernel(const int* flag, const void* ipw, const void* opw, const void* xpw,
                       int lyr, unsigned short* wtL, unsigned short* wtOl,
                       unsigned short* wtXp)
{
    __shared__ unsigned short Ts[32 * 36];
    const int bid = blockIdx.x;           // 456 = 288 inproj + 144 outproj + 24 xproj
    const int tid = threadIdx.x;
    const int r = tid >> 3, c0 = (tid & 7) * 4;
    const int BF = *flag;
    if (bid < 432) {
        const void* src; size_t soff; unsigned short* dst; int N, kb, nb;
        if (bid < 288) {
            src = ipw; soff = (size_t)lyr * 294912; dst = wtL; N = 768;
            kb = bid / 24; nb = bid % 24;
        } else {
            int rel = bid - 288;
            src = opw; soff = (size_t)lyr * 147456; dst = wtOl; N = 384;
            kb = rel / 12; nb = rel % 12;
        }
#pragma unroll
        for (int i = 0; i < 4; i++) {
            size_t si = soff + (size_t)(kb * 32 + r) * N + nb * 32 + c0 + i;
            Ts[(c0 + i) * 36 + r] = f2bf(ldr(src, si, BF));
        }
        __syncthreads();
        *(us4*)(dst + (size_t)(nb * 32 + r) * 384 + kb * 32 + c0) = *(const us4*)&Ts[r * 36 + c0];
    } else {
        int rel = bid - 432;                // 24 = 12 kb x 2 nb
        int kb = rel / 2, nb = rel % 2;
        size_t soff = (size_t)lyr * 21504;
#pragma unroll
        for (int i = 0; i < 4; i++) {
            int col = nb * 32 + c0 + i;
            float v = (col < 56) ? ldr(xpw, soff + (size_t)(kb * 32 + r) * 56 + col, BF) : 0.f;
            Ts[(c0 + i) * 36 + r] = f2bf(v);
        }
        __syncthreads();
        int nrow = nb * 32 + r;
        if (nrow < 56)
            *(us4*)(wtXp + (size_t)nrow * 384 + kb * 32 + c0) = *(const us4*)&Ts[r * 36 + c0];
    }
}

// ================= MFMA GEMMs =================
// block 256 = 4 waves; block tile 32m x 32n; wave (w&1,w>>1) -> one 16x16x32 frag.
// A bf16 [M][384]; WT bf16 [N][384]. Direct global bf16x8 gathers.

template<int MODE>  // 0: in_proj -> xi bf16 | silu(z) bf16 (grid 64x24); 1: out_proj -> tok f32 += (grid 64x12)
__global__ __launch_bounds__(256)
void gemm_kernel(const unsigned short* __restrict__ A,
                 const unsigned short* __restrict__ WT,
                 void* __restrict__ out0, unsigned short* __restrict__ out1)
{
    const int tid = threadIdx.x;
    const int w = tid >> 6, lane = tid & 63;
    const int l15 = lane & 15, quad = lane >> 4;
    const int m0 = blockIdx.x * 32 + (w & 1) * 16;
    const int n0 = blockIdx.y * 32 + (w >> 1) * 16;
    f32x4 acc = {0.f, 0.f, 0.f, 0.f};
    const bf16x8* Ap = (const bf16x8*)(A + (size_t)(m0 + l15) * 384 + quad * 8);
    const bf16x8* Bp = (const bf16x8*)(WT + (size_t)(n0 + l15) * 384 + quad * 8);
#pragma unroll
    for (int kt = 0; kt < 12; kt++) {
        bf16x8 a = Ap[kt * 4];
        bf16x8 b = Bp[kt * 4];
        acc = __builtin_amdgcn_mfma_f32_16x16x32_bf16(a, b, acc, 0, 0, 0);
    }
#pragma unroll
    for (int r = 0; r < 4; r++) {
        int m = m0 + quad * 4 + r;
        int n = n0 + l15;
        float v = acc[r];
        if (MODE == 0) {
            if (n < 384) ((unsigned short*)out0)[(size_t)m * 384 + n] = f2bf(v);
            else out1[(size_t)m * 384 + (n - 384)] = f2bf(siluf(v));
        } else {
            ((float*)out0)[(size_t)m * 384 + n] += v;
        }
    }
}

// patch MFMA: 32m x 32n block tile, grid (64,12); A from x (inline cvt if f32), K=4096
template<int BF>
__device__ void patch_body(const void* __restrict__ x,
                           const unsigned short* __restrict__ WT,
                           const void* __restrict__ pb,
                           const void* __restrict__ bparams,
                           const unsigned char* __restrict__ maskp,
                           float* __restrict__ tok)
{
    const int tid = threadIdx.x;
    const int w = tid >> 6, lane = tid & 63;
    const int l15 = lane & 15, quad = lane >> 4;
    const int m0 = blockIdx.x * 32 + (w & 1) * 16;
    const int n0 = blockIdx.y * 32 + (w >> 1) * 16;
    f32x4 acc = {0.f, 0.f, 0.f, 0.f};
    size_t tb;
    {
        int t = m0 + l15;
        int b = t >> 10, l = t & 1023;
        int gh = l >> 6, gw = (l >> 3) & 7, gd = l & 7;
        tb = (size_t)b * 4194304u + (size_t)gh * 262144u + (size_t)gw * 2048u + (size_t)gd * 8u;
    }
    const bf16x8* Bp = (const bf16x8*)(WT + (size_t)(n0 + l15) * 4096 + quad * 8);
#pragma unroll 8
    for (int kt = 0; kt < 128; kt++) {
        size_t off = 256u * ((size_t)(kt >> 3) * 64 + (kt & 7)) + quad * 64;
        bf16x8 a;
        if (BF) {
            a = *(const bf16x8*)((const unsigned short*)x + tb + off);
        } else {
            const float4* s4 = (const float4*)((const float*)x + tb + off);
            float4 p = s4[0], q = s4[1];
            a[0] = (short)f2bf(p.x); a[1] = (short)f2bf(p.y);
            a[2] = (short)f2bf(p.z); a[3] = (short)f2bf(p.w);
            a[4] = (short)f2bf(q.x); a[5] = (short)f2bf(q.y);
            a[6] = (short)f2bf(q.z); a[7] = (short)f2bf(q.w);
        }
        bf16x8 b = Bp[kt * 4];
        acc = __builtin_amdgcn_mfma_f32_16x16x32_bf16(a, b, acc, 0, 0, 0);
    }
    // epilogue: + patch_b + pos_embed (closed-form coord normalization)
    const int n = n0 + l15;
    const int j = n >> 7;
    const int ii = n & 127;
    const int i0 = (ii < 64) ? ii : ii - 64;
    const float omega = exp2f(-(float)i0 * 0.20762050593046014f);  // 10000^(-i/64)
    const float pbn = ld<BF>(pb, n);
#pragma unroll
    for (int r = 0; r < 4; r++) {
        int t = m0 + quad * 4 + r;
        int b = t >> 10, l = t & 1023;
        int gh = l >> 6, gw = (l >> 3) & 7, gd = l & 7;
        float rr = ld<BF>(bparams, b * 4 + 0);
        float ar = ld<BF>(bparams, b * 4 + 1);
        float vr = ld<BF>(bparams, b * 4 + 2);
        bool mk = maskp[b] != 0;
        float cj;
        if (j == 0) {
            float dmax = (rr >= 0.f) ? 15.f * rr : 0.f;
            if (dmax == 0.f) dmax = 1.f;
            cj = (float)gh * rr / dmax;
        } else if (j == 1) {
            float amax = 4.f * fabsf(ar);
            if (amax == 0.f) amax = 1.f;
            cj = (float)(gw - 4) * ar / amax;
        } else {
            if (mk) {
                float dmx = 4.f * fabsf(vr);
                if (dmx == 0.f) dmx = 1.f;
                cj = (float)(gd - 4) * vr / dmx;
            } else {
                float dmx = (vr >= 0.f) ? 7.f * vr : 0.f;
                if (dmx == 0.f) dmx = 1.f;
                cj = (float)gd * vr / dmx;
            }
        }
        float s = cj * omega;
        float pos = (ii < 64) ? sinf(s) : cosf(s);
        tok[(size_t)t * 384 + n] = acc[r] + pbn + pos;
    }
}

__global__ __launch_bounds__(256)
void patch_kernel(const int* flag, const void* x, const unsigned short* wtP,
                  const void* pb, const void* bparams, const unsigned char* maskp,
                  float* tok)
{
    if (*flag) patch_body<1>(x, wtP, pb, bparams, maskp, tok);
    else       patch_body<0>(x, wtP, pb, bparams, maskp, tok);
}

// ---------------- layernorm: one wave per token; in tok f32 ----------------
// obf=1: write bf16 (intermediate). obf=0: final, dtype follows flag.
__global__ __launch_bounds__(64)
void ln_kernel(const int* flag, const float* __restrict__ in, const void* __restrict__ w,
               const void* __restrict__ b, int woff, void* __restrict__ out, int obf)
{
    const int BF = *flag;
    const int wbf = obf | BF;
    const int t = blockIdx.x;
    const int lane = threadIdx.x;
    float v[6];
    float s = 0.f;
#pragma unroll
    for (int i = 0; i < 6; i++) { v[i] = in[(size_t)t * 384 + lane + 64 * i]; s += v[i]; }
#pragma unroll
    for (int o = 1; o < 64; o <<= 1) s += __shfl_xor(s, o);
    const float mu = s * (1.f / 384.f);
    float s2 = 0.f;
#pragma unroll
    for (int i = 0; i < 6; i++) { float d = v[i] - mu; s2 += d * d; }
#pragma unroll
    for (int o = 1; o < 64; o <<= 1) s2 += __shfl_xor(s2, o);
    const float rstd = rsqrtf(s2 * (1.f / 384.f) + 1e-5f);
#pragma unroll
    for (int i = 0; i < 6; i++) {
        int c = lane + 64 * i;
        float o = (v[i] - mu) * rstd * ldr(w, woff + c, BF) + ldr(b, woff + c, BF);
        if (wbf) ((unsigned short*)out)[(size_t)t * 384 + c] = f2bf(o);
        else     ((float*)out)[(size_t)t * 384 + c] = o;
    }
}

// ------- causal depthwise conv(4) + silu, x_proj (via wtXp, bf16), dt_proj -------
template<int BF>
__device__ void conv_body(float* xcs, float* dblA,
                          const unsigned short* __restrict__ xi,
                          const void* __restrict__ cw, const void* __restrict__ cb,
                          const unsigned short* __restrict__ wtXp,
                          const void* __restrict__ dtw, const void* __restrict__ dtbp,
                          int lyr,
                          unsigned short* __restrict__ xc, unsigned short* __restrict__ dtv,
                          float* __restrict__ Bm, float* __restrict__ Cm)
{
    const int t = blockIdx.x;
    const int b = t >> 10, l = t & 1023;
    const int lane = threadIdx.x;
    const size_t cwo = (size_t)lyr * 1536;
    const size_t cbo = (size_t)lyr * 384;
    const size_t dto = (size_t)lyr * 9216;
#pragma unroll
    for (int ci = 0; ci < 6; ci++) {
        int c = lane + 64 * ci;
        float acc = ld<BF>(cb, cbo + c);
#pragma unroll
        for (int jj = 0; jj < 4; jj++) {
            int ls = l - 3 + jj;
            if (ls >= 0)
                acc = fmaf(bf2f(xi[(size_t)((b << 10) + ls) * 384 + c]),
                           ld<BF>(cw, cwo + c * 4 + jj), acc);
        }
        float s = siluf(acc);
        xcs[c] = s;
        xc[(size_t)t * 384 + c] = f2bf(s);
    }
    __syncthreads();
    if (lane < 56) {
        float acc = 0.f;
        const bf16x8* wp = (const bf16x8*)(wtXp + (size_t)lane * 384);
#pragma unroll 4
        for (int kt = 0; kt < 48; kt++) {
            bf16x8 w8 = wp[kt];
#pragma unroll
            for (int jj = 0; jj < 8; jj++)
                acc = fmaf(xcs[kt * 8 + jj], bf2f((unsigned short)w8[jj]), acc);
        }
        if (lane < 24) dblA[lane] = acc;
        else if (lane < 40) Bm[(size_t)t * 16 + (lane - 24)] = acc;
        else Cm[(size_t)t * 16 + (lane - 40)] = acc;
    }
    __syncthreads();
#pragma unroll
    for (int ci = 0; ci < 6; ci++) {
        int c = lane + 64 * ci;
        float acc = ld<BF>(dtbp, cbo + c);
#pragma unroll
        for (int r = 0; r < 24; r++)
            acc = fmaf(dblA[r], ld<BF>(dtw, dto + (size_t)r * 384 + c), acc);
        float sp = fmaxf(acc, 0.f) + log1pf(expf(-fabsf(acc)));  // softplus
        dtv[(size_t)t * 384 + c] = f2bf(sp);
    }
}

__global__ __launch_bounds__(64)
void conv_kernel(const int* flag, const unsigned short* xi, const void* cw, const void* cb,
                 const unsigned short* wtXp, const void* dtw, const void* dtbp, int lyr,
                 unsigned short* xc, unsigned short* dtv, float* Bm, float* Cm)
{
    __shared__ float xcs[384];
    __shared__ float dblA[24];
    if (*flag) conv_body<1>(xcs, dblA, xi, cw, cb, wtXp, dtw, dtbp, lyr, xc, dtv, Bm, Cm);
    else       conv_body<0>(xcs, dblA, xi, cw, cb, wtXp, dtw, dtbp, lyr, xc, dtv, Bm, Cm);
}

// ---------------- chunked selective scan: 16 chunks of 64 steps ----------------
template<int BF>
__device__ void scan1_body(const unsigned short* __restrict__ dt,
                           const unsigned short* __restrict__ xc,
                           const float* __restrict__ Bm, const void* __restrict__ Alog,
                           int aoff, float* __restrict__ chA, float* __restrict__ chH)
{
    const int b = blockIdx.z, ch = blockIdx.y;
    const int c = blockIdx.x * 16 + (threadIdx.x >> 4);
    const int n = threadIdx.x & 15;
    const float Ac = -expf(ld<BF>(Alog, (size_t)aoff + c * 16 + n));
    float h = 0.f, ap = 1.f;
    const int tbase = (b << 10) + ch * 64;
    for (int i = 0; i < 64; i++) {
        int t = tbase + i;
        float d = bf2f(dt[(size_t)t * 384 + c]);
        float u = bf2f(xc[(size_t)t * 384 + c]);
        float bn = Bm[(size_t)t * 16 + n];
        float dA = expf(d * Ac);
        h = fmaf(h, dA, d * u * bn);
        ap *= dA;
    }
    size_t idx = ((size_t)((b * 16 + ch) * 384 + c)) * 16 + n;
    chA[idx] = ap;
    chH[idx] = h;
}

__global__ __launch_bounds__(256)
void scan1_kernel(const int* flag, const unsigned short* dt, const unsigned short* xc,
                  const float* Bm, const void* Alog, int aoff, float* chA, float* chH)
{
    if (*flag) scan1_body<1>(dt, xc, Bm, Alog, aoff, chA, chH);
    else       scan1_body<0>(dt, xc, Bm, Alog, aoff, chA, chH);
}

// pass2: inline chunk-prefix from chA/chH, rescan, y = (sum_n h*C + u*D)*silu(z); y bf16
template<int BF>
__device__ void scan2_body(const unsigned short* __restrict__ dt,
                           const unsigned short* __restrict__ xc,
                           const float* __restrict__ Bm, const float* __restrict__ Cm,
                           const unsigned short* __restrict__ zs,
                           const void* __restrict__ Alog, const void* __restrict__ Dp,
                           int aoff, int doff,
                           const float* __restrict__ chA, const float* __restrict__ chH,
                           unsigned short* __restrict__ y)
{
    const int b = blockIdx.z, ch = blockIdx.y;
    const int c = blockIdx.x * 16 + (threadIdx.x >> 4);
    const int n = threadIdx.x & 15;
    const float Ac = -expf(ld<BF>(Alog, (size_t)aoff + c * 16 + n));
    const float dp = ld<BF>(Dp, (size_t)doff + c);
    // prefix over earlier chunks (serial fma, same order as before -> bit-identical)
    float h = 0.f;
    for (int cc = 0; cc < ch; cc++) {
        size_t id2 = ((size_t)((b * 16 + cc) * 384 + c)) * 16 + n;
        h = fmaf(chA[id2], h, chH[id2]);
    }
    const int tbase = (b << 10) + ch * 64;
    for (int i = 0; i < 64; i++) {
        int t = tbase + i;
        float d = bf2f(dt[(size_t)t * 384 + c]);
        float u = bf2f(xc[(size_t)t * 384 + c]);
        float bn = Bm[(size_t)t * 16 + n];
        float cn = Cm[(size_t)t * 16 + n];
        float dA = expf(d * Ac);
        h = fmaf(h, dA, d * u * bn);
        float p = h * cn;
        p += __shfl_xor(p, 1);
        p += __shfl_xor(p, 2);
        p += __shfl_xor(p, 4);
        p += __shfl_xor(p, 8);
        if (n == 0)
            y[(size_t)t * 384 + c] = f2bf((p + u * dp) * bf2f(zs[(size_t)t * 384 + c]));
    }
}

__global__ __launch_bounds__(256)
void scan2_kernel(const int* flag, const unsigned short* dt, const unsigned short* xc,
                  const float* Bm, const float* Cm, const unsigned short* zs,
                  const void* Alog, const void* Dp, int aoff, int doff,
                  const float* chA, const float* chH, unsigned short* y)
{
    if (*flag) scan2_body<1>(dt, xc, Bm, Cm, zs, Alog, Dp, aoff, doff, chA, chH, y);
    else       scan2_body<0>(dt, xc, Bm, Cm, zs, Alog, Dp, aoff, doff, chA, chH, y);
}

extern "C" void kernel_launch(void* const* d_in, const int* in_sizes, int n_in,
                              void* d_out, int out_size, void* d_ws, size_t ws_size,
                              hipStream_t stream) {
    const void* x        = d_in[0];
    const void* bparams  = d_in[1];
    const void* patch_w  = d_in[2];
    const void* patch_b  = d_in[3];
    const void* in_proj  = d_in[4];
    const void* conv_w   = d_in[5];
    const void* conv_b   = d_in[6];
    const void* x_proj   = d_in[7];
    const void* dt_w     = d_in[8];
    const void* dt_b     = d_in[9];
    const void* A_log    = d_in[10];
    const void* Dskip    = d_in[11];
    const void* out_proj = d_in[12];
    const void* norm_w   = d_in[13];
    const void* norm_b   = d_in[14];
    const void* fnw      = d_in[15];
    const void* fnb      = d_in[16];
    const unsigned char* maskp = (const unsigned char*)d_in[17];

    const size_t TD = (size_t)NTOK * 384;        // 786432 elements
    float* tok = (float*)d_ws;                   // f32 residual stream
    unsigned short* hbuf = (unsigned short*)(tok + TD);   // bf16 TD buffers
    unsigned short* xi   = hbuf + TD;
    unsigned short* zs   = xi + TD;
    unsigned short* xc   = zs + TD;
    unsigned short* dtb_ = xc + TD;
    unsigned short* yb   = dtb_ + TD;
    float* Bmb = (float*)(yb + TD);              // f32 2048*16
    float* Cmb = Bmb + (size_t)NTOK * 16;
    float* chA = Cmb + (size_t)NTOK * 16;        // f32 196608 each
    float* chH = chA + 196608;
    unsigned short* wtP  = (unsigned short*)(chH + 196608);  // [384][4096] bf16
    unsigned short* wtL  = wtP + (size_t)1572864;            // [768][384] bf16 (per-layer)
    unsigned short* wtOl = wtL + (size_t)294912;             // [384][384] bf16 (per-layer)
    unsigned short* wtXp = wtOl + (size_t)147456;            // [56][384] bf16 (per-layer)
    int* dflag = (int*)(wtXp + (size_t)21504);
    // total ws ~18.5MB

    detect_kernel<<<1, 1, 0, stream>>>(Dskip, dflag);
    transposeP_kernel<<<1536, 256, 0, stream>>>(dflag, patch_w, wtP);
    patch_kernel<<<dim3(64, 12), 256, 0, stream>>>(dflag, x, wtP, patch_b,
                                                   bparams, maskp, tok);

    for (int lyr = 0; lyr < 12; lyr++) {
        transposeL_kernel<<<456, 256, 0, stream>>>(dflag, in_proj, out_proj, x_proj,
                                                   lyr, wtL, wtOl, wtXp);
        ln_kernel<<<NTOK, 64, 0, stream>>>(dflag, tok, norm_w, norm_b, lyr * 384, hbuf, 1);
        gemm_kernel<0><<<dim3(64, 24), 256, 0, stream>>>(hbuf, wtL, xi, zs);
        conv_kernel<<<NTOK, 64, 0, stream>>>(
            dflag, xi, conv_w, conv_b, wtXp, dt_w, dt_b, lyr, xc, dtb_, Bmb, Cmb);
        scan1_kernel<<<dim3(24, 16, 2), 256, 0, stream>>>(
            dflag, dtb_, xc, Bmb, A_log, lyr * 384 * 16, chA, chH);
        scan2_kernel<<<dim3(24, 16, 2), 256, 0, stream>>>(
            dflag, dtb_, xc, Bmb, Cmb, zs, A_log, Dskip, lyr * 384 * 16, lyr * 384,
            chA, chH, yb);
        gemm_kernel<1><<<dim3(64, 12), 256, 0, stream>>>(yb, wtOl, tok, nullptr);
    }

    ln_kernel<<<NTOK, 64, 0, stream>>>(dflag, tok, fnw, fnb, 0, d_out, 0);
}